// Round 10
// baseline (211.181 us; speedup 1.0000x reference)
//
#include <hip/hip_runtime.h>
#include <hip/hip_bf16.h>

#define NB 32
#define NN 128
#define NE 16256
#define ND 64
#define NHID 128
#define NM 128
#define NOH 256
#define NT 2
#define EHALF 8128
#define NTILE 127        // 64-edge tiles per half (127*64 == 8128 exactly)
#define TILE_E 64

typedef short s16x8 __attribute__((ext_vector_type(8)));
typedef short s16x4 __attribute__((ext_vector_type(4)));
typedef float f32x4 __attribute__((ext_vector_type(4)));

#define MFMA16(a, b, c) __builtin_amdgcn_mfma_f32_16x16x32_bf16((a), (b), (c), 0, 0, 0)

// ---- ws layout (bytes) ----
// partial: bf16 [256][m=128][n=128]
#define PARTIAL_SZ ((size_t)256 * 128 * 128 * 2)          //  8,388,608
#define WS_RS      (PARTIAL_SZ)                           // ushort[NE][128]
#define RS_SZ      ((size_t)NE * 128 * 2)                 //  4,161,536
#define WS_RRT     (WS_RS + RS_SZ)                        // ushort[128][NE]
#define RRT_SZ     ((size_t)128 * NE * 2)                 //  4,161,536
#define WS_IWA     (WS_RRT + RRT_SZ)                      // ushort[b][half][it][h=128][n=128]
#define IWA_SZ     ((size_t)NB * 2 * 2 * 128 * 128 * 2)   //  8,388,608
// total = 25.1 MB (<= proven 32 MB)

__device__ __forceinline__ ushort f2bf(float x) {
    uint u = __float_as_uint(x);
    return (ushort)((u + 0x7fffu + ((u >> 16) & 1u)) >> 16);
}
__device__ __forceinline__ float bf2f(ushort h) {
    return __uint_as_float(((uint)h) << 16);
}
__device__ __forceinline__ float4 ldg4(const float* p) {
    return *reinterpret_cast<const float4*>(p);
}
// pack 2 f32 -> 2 bf16 in one dword (RNE), single VALU op; low word = first arg
__device__ __forceinline__ uint cvtpk(float lo, float hi) {
    uint r;
    asm("v_cvt_pk_bf16_f32 %0, %1, %2" : "=v"(r) : "v"(lo), "v"(hi));
    return r;
}
// full-granule XOR swizzle for 256B rows: byte ^= (row&15)<<4
__device__ __forceinline__ char* swz16(void* base, int row, int bir) {
    return (char*)base + row * 256 + (bir ^ ((row & 15) << 4));
}
__device__ __forceinline__ const char* swz16c(const void* base, int row, int bir) {
    return (const char*)base + row * 256 + (bir ^ ((row & 15) << 4));
}
// 8-granule XOR swizzle for 128B rows: byte ^= (row&7)<<4
__device__ __forceinline__ char* swz8(void* base, int row, int bir) {
    return (char*)base + row * 128 + (bir ^ ((row & 7) << 4));
}
__device__ __forceinline__ const char* swz8c(const void* base, int row, int bir) {
    return (const char*)base + row * 128 + (bir ^ ((row & 7) << 4));
}
// async 16B global->LDS (dest lane-linear; source pre-swizzled per G21)
__device__ __forceinline__ void gload16(const void* g, void* l) {
    __builtin_amdgcn_global_load_lds(
        (const __attribute__((address_space(1))) void*)g,
        (__attribute__((address_space(3))) void*)l, 16, 0, 0);
}

// ---------------------------------------------------------------------------
// k_pre: fused conversions + inpWA precompute (unchanged from round 9).
// ---------------------------------------------------------------------------
__global__ __launch_bounds__(256)
void k_pre(const float* __restrict__ inputs,
           const float* __restrict__ rel_rec, const float* __restrict__ rel_send,
           const float* __restrict__ w1, const float* __restrict__ w3,
           char* __restrict__ ws)
{
    ushort* rs  = (ushort*)(ws + WS_RS);
    ushort* rrT = (ushort*)(ws + WS_RRT);
    const int t = threadIdx.x;
    const int blk = blockIdx.x;
    __shared__ float lds[128][65];

    if (blk < 127) {                       // rrT: transpose rel_rec -> [n][e] bf16
        const int eb = blk;
        for (int nh = 0; nh < 2; ++nh) {
            __syncthreads();
            for (int i = t; i < 128 * 64; i += 256) {
                int e = i >> 6, n = i & 63;
                lds[e][n] = rel_rec[(size_t)(eb * 128 + e) * 128 + nh * 64 + n];
            }
            __syncthreads();
            for (int i = t; i < 64 * 128; i += 256) {
                int n = i >> 7, e = i & 127;
                rrT[(size_t)(nh * 64 + n) * NE + eb * 128 + e] = f2bf(lds[e][n]);
            }
        }
    } else if (blk < 254) {                // rs: straight convert
        const int eb = blk - 127;
        const float4* src = (const float4*)(rel_send + (size_t)eb * 16384);
        for (int i = t; i < 4096; i += 256) {
            float4 v = src[i];
            ushort4 o;
            o.x = f2bf(v.x); o.y = f2bf(v.y); o.z = f2bf(v.z); o.w = f2bf(v.w);
            *(ushort4*)(rs + (size_t)eb * 16384 + (size_t)i * 4) = o;
        }
    } else {                               // inpWA precompute (MFMA)
        ushort* iwa = (ushort*)(ws + WS_IWA);
        const int wg = blk - 254;          // 0..127
        const int b = wg >> 2, half = (wg >> 1) & 1, it = wg & 1;
        const float* WA  = (half ? w3 : w1) + (size_t)it * NHID * ND;
        const float* inp = inputs + (size_t)b * NN * ND;
        ushort* dst = iwa + (size_t)wg * NHID * NN;    // [h][n]

        const int lane = t & 63, wave = t >> 6;
        const int l16 = lane & 15, l4 = lane >> 4;

        for (int hh = 0; hh < 2; ++hh) {
            const int ht = wave * 2 + hh;
            s16x8 bf[2];
#pragma unroll
            for (int ks = 0; ks < 2; ++ks) {
                const float* p = WA + (size_t)(ht * 16 + l16) * ND + ks * 32 + l4 * 8;
                float4 u = ldg4(p), v = ldg4(p + 4);
                s16x8 f;
                f[0] = (short)f2bf(u.x); f[1] = (short)f2bf(u.y);
                f[2] = (short)f2bf(u.z); f[3] = (short)f2bf(u.w);
                f[4] = (short)f2bf(v.x); f[5] = (short)f2bf(v.y);
                f[6] = (short)f2bf(v.z); f[7] = (short)f2bf(v.w);
                bf[ks] = f;
            }
            for (int nt = 0; nt < 8; ++nt) {
                s16x8 af[2];
#pragma unroll
                for (int ks = 0; ks < 2; ++ks) {
                    const float* p = inp + (size_t)(nt * 16 + l16) * ND + ks * 32 + l4 * 8;
                    float4 u = ldg4(p), v = ldg4(p + 4);
                    s16x8 f;
                    f[0] = (short)f2bf(u.x); f[1] = (short)f2bf(u.y);
                    f[2] = (short)f2bf(u.z); f[3] = (short)f2bf(u.w);
                    f[4] = (short)f2bf(v.x); f[5] = (short)f2bf(v.y);
                    f[6] = (short)f2bf(v.z); f[7] = (short)f2bf(v.w);
                    af[ks] = f;
                }
                f32x4 c = (f32x4){0.f, 0.f, 0.f, 0.f};
                c = MFMA16(af[0], bf[0], c);
                c = MFMA16(af[1], bf[1], c);
                s16x4 o;
                o[0] = (short)f2bf(c[0]); o[1] = (short)f2bf(c[1]);
                o[2] = (short)f2bf(c[2]); o[3] = (short)f2bf(c[3]);
                *(s16x4*)&dst[(size_t)(ht * 16 + l16) * NN + nt * 16 + l4 * 4] = o;
            }
        }
    }
}

// ---------------------------------------------------------------------------
// k_edge: grid 256 = b*8 + half*4 + chunk(4). block 512 (8 waves), 1 block/CU.
// Squarer per-wave tiles (32x32 via 2x2 of 16x16 MFMA) to halve LDS A-traffic.
//   P(t): issue gload rr(t)->rr[buf], rs(t+1)->rs[nbuf]; rt(t);
//         H-phase: wave (we2,wc4) owns e[we*32..)+h[wc*32..)       | bar1
//   M-phase: wave (we2,wc4) owns e[we*32..)+m[wc*32..); Mt writes  | bar2
//   agg-phase: wave (wn4,wm2) owns n[wn*32..)+m[wm*64..)
// Register plan (~230 < 256 cap @ (512,1)): wIW 64 + wB 64 + agg 32(AGPR)
// + transients. If FETCH_SIZE balloons -> spilled -> revert.
// ---------------------------------------------------------------------------
__global__ __launch_bounds__(512, 1)
void k_edge(const float* __restrict__ rel_type,
            const float* __restrict__ b1, const float* __restrict__ b2,
            const float* __restrict__ b3, const float* __restrict__ b4,
            const float* __restrict__ w2, const float* __restrict__ w4,
            char* __restrict__ ws)
{
    const ushort* rsg = (const ushort*)(ws + WS_RS);
    const ushort* rrT = (const ushort*)(ws + WS_RRT);
    const ushort* iwa = (const ushort*)(ws + WS_IWA);
    ushort* partial   = (ushort*)ws;

    const int tid  = threadIdx.x;
    const int wave = tid >> 6;
    const int lane = tid & 63;
    const int l16  = lane & 15;
    const int l4   = lane >> 4;
    const int we   = wave >> 2;   // H/M: e-block 0..1
    const int wc   = wave & 3;    // H/M: h/m-block 0..3
    const int wn   = wave & 3;    // agg: n-block 0..3
    const int wm   = wave >> 2;   // agg: m-half 0..1

    const int wg    = blockIdx.x;
    const int b     = wg >> 3;
    const int half  = (wg >> 2) & 1;
    const int chunk = wg & 3;

    const float* BA    = half ? b3 : b1;
    const float* BB    = half ? b4 : b2;
    const float* WBsrc = half ? w4 : w2;

    __shared__ ushort H_s[2][64 * 128];     // [it][e][h] 32 KB, 256B rows
    __shared__ ushort rs_s[2][64 * 128];    // [e][n] 32 KB, 256B rows
    __shared__ ushort rr_s[2][128 * 64];    // [n][e] 32 KB, 128B rows
    __shared__ ushort Mt_s[128 * 64];       // [m][e] 16 KB, 128B rows
    __shared__ float  rt_s[2][128];         //  1 KB
    // total 113 KB -> 1 block/CU (structural)

    // persistent B-fragments
    s16x8 wIW[2][2][4];   // [it][hti][ks], h-col = wc*32+hti*16+l16, k=n
    const ushort* iwb = iwa + (size_t)((b * 2 + half) * 2) * NHID * NN;
#pragma unroll
    for (int it = 0; it < 2; ++it)
#pragma unroll
        for (int hti = 0; hti < 2; ++hti)
#pragma unroll
            for (int ks = 0; ks < 4; ++ks)
                wIW[it][hti][ks] = *(const s16x8*)(iwb + (size_t)it * NHID * NN +
                    (size_t)(wc * 32 + hti * 16 + l16) * NN + ks * 32 + l4 * 8);
    s16x8 wB[2][2][4];    // [it][mti][ks], m-col = wc*32+mti*16+l16, k=h
#pragma unroll
    for (int it = 0; it < 2; ++it)
#pragma unroll
        for (int mti = 0; mti < 2; ++mti)
#pragma unroll
            for (int ks = 0; ks < 4; ++ks) {
                const float* p = WBsrc +
                    (size_t)(it * NM + wc * 32 + mti * 16 + l16) * NHID + ks * 32 + l4 * 8;
                float4 u = ldg4(p), v = ldg4(p + 4);
                s16x8 f;
                f[0] = (short)f2bf(u.x); f[1] = (short)f2bf(u.y);
                f[2] = (short)f2bf(u.z); f[3] = (short)f2bf(u.w);
                f[4] = (short)f2bf(v.x); f[5] = (short)f2bf(v.y);
                f[6] = (short)f2bf(v.z); f[7] = (short)f2bf(v.w);
                wB[it][mti][ks] = f;
            }
    float biasA[2][2], biasB[2][2];
#pragma unroll
    for (int it = 0; it < 2; ++it)
#pragma unroll
        for (int q = 0; q < 2; ++q) {
            biasA[it][q] = BA[it * NHID + wc * 32 + q * 16 + l16];
            biasB[it][q] = BB[it * NM + wc * 32 + q * 16 + l16];
        }

    f32x4 agg[2][4];      // [nti][mti]
#pragma unroll
    for (int i = 0; i < 2; ++i)
#pragma unroll
        for (int j = 0; j < 4; ++j) agg[i][j] = (f32x4){0.f, 0.f, 0.f, 0.f};

    const int t0 = chunk * 32;
    const int t1 = (t0 + 32 < NTILE) ? (t0 + 32) : NTILE;

    // ---- prologue: stage rs(t0) into buf0 ----
    {
        const int ebase0 = half * EHALF + t0 * TILE_E;
#pragma unroll
        for (int s = 0; s < 2; ++s) {
            const int i = s * 512 + tid;
            const int e = i >> 4, c = i & 15;
            const int cp = c ^ (e & 15);
            gload16(rsg + (size_t)(ebase0 + e) * 128 + cp * 8, (char*)&rs_s[0][0] + i * 16);
        }
    }
    __syncthreads();

    for (int t = t0; t < t1; ++t) {
        const int buf  = (t - t0) & 1;
        const int nbuf = buf ^ 1;
        const int ebase = half * EHALF + t * TILE_E;
        const bool do_next = (t + 1) < t1;

        // ---- P(t): staging issues ----
#pragma unroll
        for (int s = 0; s < 2; ++s) {
            const int j = s * 512 + tid;
            const int n = j >> 3, c = j & 7;
            const int cp = c ^ (n & 7);
            gload16(rrT + (size_t)n * NE + ebase + cp * 8, (char*)&rr_s[buf][0] + j * 16);
        }
        if (do_next) {
            const int ebn = ebase + TILE_E;
#pragma unroll
            for (int s = 0; s < 2; ++s) {
                const int i = s * 512 + tid;
                const int e = i >> 4, c = i & 15;
                const int cp = c ^ (e & 15);
                gload16(rsg + (size_t)(ebn + e) * 128 + cp * 8, (char*)&rs_s[nbuf][0] + i * 16);
            }
        }
        if (tid < 128)
            rt_s[buf][tid] = rel_type[((size_t)b * NE + ebase + (tid >> 1)) * NT + (tid & 1)];

        // ---- H-phase: H[it] = relu(RS @ inpWA[it] + bA), wave tile 32e x 32h
#pragma unroll
        for (int eti = 0; eti < 2; ++eti) {
            const int er = we * 32 + eti * 16;
            s16x8 a0 = *(const s16x8*)swz16c(&rs_s[buf][0], er + l16, 0 * 64 + l4 * 16);
            s16x8 a1 = *(const s16x8*)swz16c(&rs_s[buf][0], er + l16, 1 * 64 + l4 * 16);
            s16x8 a2 = *(const s16x8*)swz16c(&rs_s[buf][0], er + l16, 2 * 64 + l4 * 16);
            s16x8 a3 = *(const s16x8*)swz16c(&rs_s[buf][0], er + l16, 3 * 64 + l4 * 16);
#pragma unroll
            for (int it = 0; it < 2; ++it) {
#pragma unroll
                for (int hti = 0; hti < 2; ++hti) {
                    f32x4 c = (f32x4){0.f, 0.f, 0.f, 0.f};
                    __builtin_amdgcn_s_setprio(1);
                    c = MFMA16(a0, wIW[it][hti][0], c);
                    c = MFMA16(a1, wIW[it][hti][1], c);
                    c = MFMA16(a2, wIW[it][hti][2], c);
                    c = MFMA16(a3, wIW[it][hti][3], c);
                    __builtin_amdgcn_s_setprio(0);
                    const int hcol = wc * 32 + hti * 16 + l16;
#pragma unroll
                    for (int r = 0; r < 4; ++r) {
                        const int er2 = er + l4 * 4 + r;
                        *(ushort*)swz16(&H_s[it][0], er2, hcol * 2) =
                            (ushort)cvtpk(fmaxf(c[r] + biasA[it][hti], 0.f), 0.f);
                    }
                }
            }
        }
        __syncthreads();                                   // bar1

        // ---- M-phase: wave tile 32e x 32m; macc summed over it ----
        f32x4 macc[2][2];
#pragma unroll
        for (int i = 0; i < 2; ++i)
#pragma unroll
            for (int j = 0; j < 2; ++j) macc[i][j] = (f32x4){0.f, 0.f, 0.f, 0.f};
        float2 rtv[2][4];
#pragma unroll
        for (int eti = 0; eti < 2; ++eti)
#pragma unroll
            for (int r = 0; r < 4; ++r)
                rtv[eti][r] = *(const float2*)&rt_s[buf][(we * 32 + eti * 16 + l4 * 4 + r) * 2];

#pragma unroll
        for (int it = 0; it < 2; ++it) {
#pragma unroll
            for (int eti = 0; eti < 2; ++eti) {
                const int e = we * 32 + eti * 16 + l16;
                s16x8 a0 = *(const s16x8*)swz16c(&H_s[it][0], e, 0 * 64 + l4 * 16);
                s16x8 a1 = *(const s16x8*)swz16c(&H_s[it][0], e, 1 * 64 + l4 * 16);
                s16x8 a2 = *(const s16x8*)swz16c(&H_s[it][0], e, 2 * 64 + l4 * 16);
                s16x8 a3 = *(const s16x8*)swz16c(&H_s[it][0], e, 3 * 64 + l4 * 16);
#pragma unroll
                for (int mti = 0; mti < 2; ++mti) {
                    f32x4 c = (f32x4){0.f, 0.f, 0.f, 0.f};
                    __builtin_amdgcn_s_setprio(1);
                    c = MFMA16(a0, wB[it][mti][0], c);
                    c = MFMA16(a1, wB[it][mti][1], c);
                    c = MFMA16(a2, wB[it][mti][2], c);
                    c = MFMA16(a3, wB[it][mti][3], c);
                    __builtin_amdgcn_s_setprio(0);
#pragma unroll
                    for (int r = 0; r < 4; ++r)
                        macc[eti][mti][r] += fmaxf(c[r] + biasB[it][mti], 0.f) *
                                             (it ? rtv[eti][r].y : rtv[eti][r].x);
                }
            }
        }
        // Mt writes [m][e]
#pragma unroll
        for (int eti = 0; eti < 2; ++eti)
#pragma unroll
            for (int mti = 0; mti < 2; ++mti) {
                const int m = wc * 32 + mti * 16 + l16;
                uint2 v;
                v.x = cvtpk(macc[eti][mti][0], macc[eti][mti][1]);
                v.y = cvtpk(macc[eti][mti][2], macc[eti][mti][3]);
                *(uint2*)swz8(Mt_s, m, (we * 32 + eti * 16 + l4 * 4) * 2) = v;
            }
        __syncthreads();                                   // bar2

        // ---- agg-phase: wave tile 32n x 64m ----
#pragma unroll
        for (int ks = 0; ks < 2; ++ks) {
            s16x8 aa0 = *(const s16x8*)swz8c(&rr_s[buf][0], wn * 32 + 0 * 16 + l16, ks * 64 + l4 * 16);
            s16x8 aa1 = *(const s16x8*)swz8c(&rr_s[buf][0], wn * 32 + 1 * 16 + l16, ks * 64 + l4 * 16);
            s16x8 bb0 = *(const s16x8*)swz8c(Mt_s, wm * 64 + 0 * 16 + l16, ks * 64 + l4 * 16);
            s16x8 bb1 = *(const s16x8*)swz8c(Mt_s, wm * 64 + 1 * 16 + l16, ks * 64 + l4 * 16);
            s16x8 bb2 = *(const s16x8*)swz8c(Mt_s, wm * 64 + 2 * 16 + l16, ks * 64 + l4 * 16);
            s16x8 bb3 = *(const s16x8*)swz8c(Mt_s, wm * 64 + 3 * 16 + l16, ks * 64 + l4 * 16);
            __builtin_amdgcn_s_setprio(1);
            agg[0][0] = MFMA16(aa0, bb0, agg[0][0]);
            agg[0][1] = MFMA16(aa0, bb1, agg[0][1]);
            agg[0][2] = MFMA16(aa0, bb2, agg[0][2]);
            agg[0][3] = MFMA16(aa0, bb3, agg[0][3]);
            agg[1][0] = MFMA16(aa1, bb0, agg[1][0]);
            agg[1][1] = MFMA16(aa1, bb1, agg[1][1]);
            agg[1][2] = MFMA16(aa1, bb2, agg[1][2]);
            agg[1][3] = MFMA16(aa1, bb3, agg[1][3]);
            __builtin_amdgcn_s_setprio(0);
        }
    }

    // store bf16 partialT [wg][m][n]
    {
        ushort* dst = partial + (size_t)wg * (NN * NM);
#pragma unroll
        for (int nti = 0; nti < 2; ++nti)
#pragma unroll
            for (int mti = 0; mti < 4; ++mti) {
                const int m  = wm * 64 + mti * 16 + l16;
                const int n0 = wn * 32 + nti * 16 + l4 * 4;
                uint2 v;
                v.x = cvtpk(agg[nti][mti][0], agg[nti][mti][1]);
                v.y = cvtpk(agg[nti][mti][2], agg[nti][mti][3]);
                *(uint2*)&dst[(size_t)m * NN + n0] = v;
            }
    }
}

// ---------------------------------------------------------------------------
// k_out: reduce 8 bf16 partials -> node MLP 128->256->256->64 + residual
// ---------------------------------------------------------------------------
__global__ __launch_bounds__(256)
void k_out(const ushort* __restrict__ partial,
           const float* __restrict__ inputs,
           const float* __restrict__ ow1, const float* __restrict__ ob1,
           const float* __restrict__ ow2, const float* __restrict__ ob2,
           const float* __restrict__ ow3, const float* __restrict__ ob3,
           float* __restrict__ out)
{
    const int t  = threadIdx.x;
    const int wg = blockIdx.x;      // 0..255
    const int b  = wg >> 3;
    const int n0 = (wg & 7) * 16;

    __shared__ float xr[16 * NM];
    __shared__ float h1[16 * NOH];
    __shared__ float h2[16 * NOH];

    // reduce 8 partials (transposed layout [m][n])
    for (int u = t; u < 512; u += 256) {
        const int m = u >> 2, g = u & 3;
        float s0 = 0.f, s1 = 0.f, s2 = 0.f, s3 = 0.f;
#pragma unroll
        for (int c = 0; c < 8; ++c) {
            const ushort* p = partial + ((size_t)(b * 8 + c)) * (NN * NM) +
                              (size_t)m * NN + n0 + g * 4;
            s16x4 v = *(const s16x4*)p;
            s0 += bf2f((ushort)v[0]); s1 += bf2f((ushort)v[1]);
            s2 += bf2f((ushort)v[2]); s3 += bf2f((ushort)v[3]);
        }
        xr[(g * 4 + 0) * NM + m] = s0;
        xr[(g * 4 + 1) * NM + m] = s1;
        xr[(g * 4 + 2) * NM + m] = s2;
        xr[(g * 4 + 3) * NM + m] = s3;
    }
    __syncthreads();

    {
        float acc[16];
        const float bias = ob1[t];
#pragma unroll
        for (int r = 0; r < 16; ++r) acc[r] = bias;
        const float* wrow = ow1 + (size_t)t * NM;
#pragma unroll 2
        for (int mq = 0; mq < NM / 4; ++mq) {
            const float4 w = ldg4(wrow + mq * 4);
#pragma unroll
            for (int r = 0; r < 16; ++r) {
                const float4 xv = *reinterpret_cast<const float4*>(&xr[r * NM + mq * 4]);
                acc[r] += xv.x * w.x + xv.y * w.y + xv.z * w.z + xv.w * w.w;
            }
        }
#pragma unroll
        for (int r = 0; r < 16; ++r) h1[r * NOH + t] = fmaxf(acc[r], 0.f);
    }
    __syncthreads();

    {
        float acc[16];
        const float bias = ob2[t];
#pragma unroll
        for (int r = 0; r < 16; ++r) acc[r] = bias;
        const float* wrow = ow2 + (size_t)t * NOH;
#pragma unroll 2
        for (int hq = 0; hq < NOH / 4; ++hq) {
            const float4 w = ldg4(wrow + hq * 4);
#pragma unroll
            for (int r = 0; r < 16; ++r) {
                const float4 hv = *reinterpret_cast<const float4*>(&h1[r * NOH + hq * 4]);
                acc[r] += hv.x * w.x + hv.y * w.y + hv.z * w.z + hv.w * w.w;
            }
        }
#pragma unroll
        for (int r = 0; r < 16; ++r) h2[r * NOH + t] = fmaxf(acc[r], 0.f);
    }
    __syncthreads();

    {
        const int d  = t & 63;
        const int rg = t >> 6;
        float acc[4] = {0.f, 0.f, 0.f, 0.f};
        const float* wrow = ow3 + (size_t)d * NOH;
#pragma unroll 2
        for (int hq = 0; hq < NOH / 4; ++hq) {
            const float4 w = ldg4(wrow + hq * 4);
#pragma unroll
            for (int r = 0; r < 4; ++r) {
                const float4 hv = *reinterpret_cast<const float4*>(&h2[(rg * 4 + r) * NOH + hq * 4]);
                acc[r] += hv.x * w.x + hv.y * w.y + hv.z * w.z + hv.w * w.w;
            }
        }
        const float bias = ob3[d];
#pragma unroll
        for (int r = 0; r < 4; ++r) {
            const int n = n0 + rg * 4 + r;
            const size_t idx = ((size_t)b * NN + n) * ND + d;
            out[idx] = inputs[idx] + acc[r] + bias;
        }
    }
}

extern "C" void kernel_launch(void* const* d_in, const int* in_sizes, int n_in,
                              void* d_out, int out_size, void* d_ws, size_t ws_size,
                              hipStream_t stream)
{
    const float* inputs   = (const float*)d_in[0];
    const float* rel_rec  = (const float*)d_in[1];
    const float* rel_send = (const float*)d_in[2];
    const float* rel_type = (const float*)d_in[3];
    const float* w1  = (const float*)d_in[5];
    const float* b1  = (const float*)d_in[6];
    const float* w2  = (const float*)d_in[7];
    const float* b2  = (const float*)d_in[8];
    const float* w3  = (const float*)d_in[9];
    const float* b3  = (const float*)d_in[10];
    const float* w4  = (const float*)d_in[11];
    const float* b4  = (const float*)d_in[12];
    const float* ow1 = (const float*)d_in[13];
    const float* ob1 = (const float*)d_in[14];
    const float* ow2 = (const float*)d_in[15];
    const float* ob2 = (const float*)d_in[16];
    const float* ow3 = (const float*)d_in[17];
    const float* ob3 = (const float*)d_in[18];

    char* ws = (char*)d_ws;

    k_pre <<<dim3(382), dim3(256), 0, stream>>>(inputs, rel_rec, rel_send,
                                                w1, w3, ws);
    k_edge<<<dim3(256), dim3(512), 0, stream>>>(rel_type,
                                                b1, b2, b3, b4, w2, w4, ws);
    k_out <<<dim3(256), dim3(256), 0, stream>>>((const ushort*)ws, inputs,
                                                ow1, ob1, ow2, ob2, ow3, ob3,
                                                (float*)d_out);
}

// Round 11
// 197.578 us; speedup vs baseline: 1.0689x; 1.0689x over previous
//
#include <hip/hip_runtime.h>
#include <hip/hip_bf16.h>

#define NB 32
#define NN 128
#define NE 16256
#define ND 64
#define NHID 128
#define NM 128
#define NOH 256
#define NT 2
#define EHALF 8128
#define NTILE 127        // 64-edge tiles per half (127*64 == 8128 exactly)
#define TILE_E 64

typedef short s16x8 __attribute__((ext_vector_type(8)));
typedef short s16x4 __attribute__((ext_vector_type(4)));
typedef float f32x4 __attribute__((ext_vector_type(4)));

#define MFMA16(a, b, c) __builtin_amdgcn_mfma_f32_16x16x32_bf16((a), (b), (c), 0, 0, 0)

// ---- ws layout (bytes) ----
// partial: bf16 [256][m=128][n=128]
#define PARTIAL_SZ ((size_t)256 * 128 * 128 * 2)          //  8,388,608
#define WS_RS      (PARTIAL_SZ)                           // ushort[NE][128]
#define RS_SZ      ((size_t)NE * 128 * 2)                 //  4,161,536
#define WS_RRT     (WS_RS + RS_SZ)                        // ushort[128][NE]
#define RRT_SZ     ((size_t)128 * NE * 2)                 //  4,161,536
#define WS_IWA     (WS_RRT + RRT_SZ)                      // ushort[b][half][it][h=128][n=128]
#define IWA_SZ     ((size_t)NB * 2 * 2 * 128 * 128 * 2)   //  8,388,608
#define WS_OW      (WS_IWA + IWA_SZ)                      // bf16 ow1[256*128] ow2[256*256] ow3[64*256]
#define OW_SZ      ((size_t)(32768 + 65536 + 16384) * 2)  //    229,376
// total = 25.3 MB (<= proven 32 MB)

__device__ __forceinline__ ushort f2bf(float x) {
    uint u = __float_as_uint(x);
    return (ushort)((u + 0x7fffu + ((u >> 16) & 1u)) >> 16);
}
__device__ __forceinline__ float bf2f(ushort h) {
    return __uint_as_float(((uint)h) << 16);
}
__device__ __forceinline__ float4 ldg4(const float* p) {
    return *reinterpret_cast<const float4*>(p);
}
// pack 2 f32 -> 2 bf16 in one dword (RNE), single VALU op; low word = first arg
__device__ __forceinline__ uint cvtpk(float lo, float hi) {
    uint r;
    asm("v_cvt_pk_bf16_f32 %0, %1, %2" : "=v"(r) : "v"(lo), "v"(hi));
    return r;
}
// full-granule XOR swizzle for 256B rows: byte ^= (row&15)<<4
__device__ __forceinline__ char* swz16(void* base, int row, int bir) {
    return (char*)base + row * 256 + (bir ^ ((row & 15) << 4));
}
__device__ __forceinline__ const char* swz16c(const void* base, int row, int bir) {
    return (const char*)base + row * 256 + (bir ^ ((row & 15) << 4));
}
// 8-granule XOR swizzle for 128B rows: byte ^= (row&7)<<4
__device__ __forceinline__ char* swz8(void* base, int row, int bir) {
    return (char*)base + row * 128 + (bir ^ ((row & 7) << 4));
}
__device__ __forceinline__ const char* swz8c(const void* base, int row, int bir) {
    return (const char*)base + row * 128 + (bir ^ ((row & 7) << 4));
}
// generic-rowBytes variant (k_out h buffers, 512B rows)
__device__ __forceinline__ char* swzR(void* base, int row, int rowBytes, int bir) {
    return (char*)base + row * rowBytes + (bir ^ ((row & 15) << 4));
}
__device__ __forceinline__ const char* swzRc(const void* base, int row, int rowBytes, int bir) {
    return (const char*)base + row * rowBytes + (bir ^ ((row & 15) << 4));
}
// async 16B global->LDS (dest lane-linear; source pre-swizzled per G21)
__device__ __forceinline__ void gload16(const void* g, void* l) {
    __builtin_amdgcn_global_load_lds(
        (const __attribute__((address_space(1))) void*)g,
        (__attribute__((address_space(3))) void*)l, 16, 0, 0);
}

// ---------------------------------------------------------------------------
// k_pre: fused conversions + inpWA precompute + node-weight bf16 conversion.
// blocks 0..126: rrT transpose+convert; 127..253: rs convert;
// blocks 254..381: inpWA; block 382: ow1/ow2/ow3 -> bf16
// ---------------------------------------------------------------------------
__global__ __launch_bounds__(256)
void k_pre(const float* __restrict__ inputs,
           const float* __restrict__ rel_rec, const float* __restrict__ rel_send,
           const float* __restrict__ w1, const float* __restrict__ w3,
           const float* __restrict__ ow1, const float* __restrict__ ow2,
           const float* __restrict__ ow3,
           char* __restrict__ ws)
{
    ushort* rs  = (ushort*)(ws + WS_RS);
    ushort* rrT = (ushort*)(ws + WS_RRT);
    const int t = threadIdx.x;
    const int blk = blockIdx.x;
    __shared__ float lds[128][65];

    if (blk < 127) {                       // rrT: transpose rel_rec -> [n][e] bf16
        const int eb = blk;
        for (int nh = 0; nh < 2; ++nh) {
            __syncthreads();
            for (int i = t; i < 128 * 64; i += 256) {
                int e = i >> 6, n = i & 63;
                lds[e][n] = rel_rec[(size_t)(eb * 128 + e) * 128 + nh * 64 + n];
            }
            __syncthreads();
            for (int i = t; i < 64 * 128; i += 256) {
                int n = i >> 7, e = i & 127;
                rrT[(size_t)(nh * 64 + n) * NE + eb * 128 + e] = f2bf(lds[e][n]);
            }
        }
    } else if (blk < 254) {                // rs: straight convert
        const int eb = blk - 127;
        const float4* src = (const float4*)(rel_send + (size_t)eb * 16384);
        for (int i = t; i < 4096; i += 256) {
            float4 v = src[i];
            ushort4 o;
            o.x = f2bf(v.x); o.y = f2bf(v.y); o.z = f2bf(v.z); o.w = f2bf(v.w);
            *(ushort4*)(rs + (size_t)eb * 16384 + (size_t)i * 4) = o;
        }
    } else if (blk < 382) {                // inpWA precompute (MFMA)
        ushort* iwa = (ushort*)(ws + WS_IWA);
        const int wg = blk - 254;          // 0..127
        const int b = wg >> 2, half = (wg >> 1) & 1, it = wg & 1;
        const float* WA  = (half ? w3 : w1) + (size_t)it * NHID * ND;
        const float* inp = inputs + (size_t)b * NN * ND;
        ushort* dst = iwa + (size_t)wg * NHID * NN;    // [h][n]

        const int lane = t & 63, wave = t >> 6;
        const int l16 = lane & 15, l4 = lane >> 4;

        for (int hh = 0; hh < 2; ++hh) {
            const int ht = wave * 2 + hh;
            s16x8 bf[2];
#pragma unroll
            for (int ks = 0; ks < 2; ++ks) {
                const float* p = WA + (size_t)(ht * 16 + l16) * ND + ks * 32 + l4 * 8;
                float4 u = ldg4(p), v = ldg4(p + 4);
                s16x8 f;
                f[0] = (short)f2bf(u.x); f[1] = (short)f2bf(u.y);
                f[2] = (short)f2bf(u.z); f[3] = (short)f2bf(u.w);
                f[4] = (short)f2bf(v.x); f[5] = (short)f2bf(v.y);
                f[6] = (short)f2bf(v.z); f[7] = (short)f2bf(v.w);
                bf[ks] = f;
            }
            for (int nt = 0; nt < 8; ++nt) {
                s16x8 af[2];
#pragma unroll
                for (int ks = 0; ks < 2; ++ks) {
                    const float* p = inp + (size_t)(nt * 16 + l16) * ND + ks * 32 + l4 * 8;
                    float4 u = ldg4(p), v = ldg4(p + 4);
                    s16x8 f;
                    f[0] = (short)f2bf(u.x); f[1] = (short)f2bf(u.y);
                    f[2] = (short)f2bf(u.z); f[3] = (short)f2bf(u.w);
                    f[4] = (short)f2bf(v.x); f[5] = (short)f2bf(v.y);
                    f[6] = (short)f2bf(v.z); f[7] = (short)f2bf(v.w);
                    af[ks] = f;
                }
                f32x4 c = (f32x4){0.f, 0.f, 0.f, 0.f};
                c = MFMA16(af[0], bf[0], c);
                c = MFMA16(af[1], bf[1], c);
                s16x4 o;
                o[0] = (short)f2bf(c[0]); o[1] = (short)f2bf(c[1]);
                o[2] = (short)f2bf(c[2]); o[3] = (short)f2bf(c[3]);
                *(s16x4*)&dst[(size_t)(ht * 16 + l16) * NN + nt * 16 + l4 * 4] = o;
            }
        }
    } else {                               // node weights -> bf16
        ushort* owbf = (ushort*)(ws + WS_OW);
        for (int i = t; i < 114688; i += 256) {
            float v;
            if (i < 32768)       v = ow1[i];
            else if (i < 98304)  v = ow2[i - 32768];
            else                 v = ow3[i - 98304];
            owbf[i] = f2bf(v);
        }
    }
}

// ---------------------------------------------------------------------------
// k_edge: ROUND-9 VERBATIM (proven 122 us). grid 256, block 512, 1 block/CU.
// One barrier/tile; gload_lds staging w/ pre-swizzled src; (row&15)<<4 swizzle
// on 256B rows; wave-private Mt roundtrip; cvtpk packing.
// ---------------------------------------------------------------------------
__global__ __launch_bounds__(512, 1)
void k_edge(const float* __restrict__ rel_type,
            const float* __restrict__ b1, const float* __restrict__ b2,
            const float* __restrict__ b3, const float* __restrict__ b4,
            const float* __restrict__ w2, const float* __restrict__ w4,
            char* __restrict__ ws)
{
    const ushort* rsg = (const ushort*)(ws + WS_RS);
    const ushort* rrT = (const ushort*)(ws + WS_RRT);
    const ushort* iwa = (const ushort*)(ws + WS_IWA);
    ushort* partial   = (ushort*)ws;

    const int tid  = threadIdx.x;
    const int wave = tid >> 6;
    const int lane = tid & 63;
    const int l16  = lane & 15;
    const int l4   = lane >> 4;

    const int wg    = blockIdx.x;
    const int b     = wg >> 3;
    const int half  = (wg >> 2) & 1;
    const int chunk = wg & 3;

    const float* BA    = half ? b3 : b1;
    const float* BB    = half ? b4 : b2;
    const float* WBsrc = half ? w4 : w2;

    __shared__ ushort H_s[2][2][64 * 128];  // 64 KB (buf, it), 256B rows
    __shared__ ushort rs_s[2][64 * 128];    // 32 KB, 256B rows
    __shared__ ushort rr_s[2][128 * 64];    // 32 KB, 128B rows
    __shared__ ushort Mt_s[128 * 64];       // 16 KB, 128B rows, wave-private
    __shared__ float  rt_s[2][128];         //  1 KB

    s16x8 wIW[2][4];
    const ushort* iwb = iwa + (size_t)((b * 2 + half) * 2) * NHID * NN;
#pragma unroll
    for (int it = 0; it < 2; ++it)
#pragma unroll
        for (int ks = 0; ks < 4; ++ks)
            wIW[it][ks] = *(const s16x8*)(iwb + (size_t)it * NHID * NN +
                                          (size_t)(wave * 16 + l16) * NN + ks * 32 + l4 * 8);
    s16x8 wB[2][4];
#pragma unroll
    for (int it = 0; it < 2; ++it)
#pragma unroll
        for (int ks = 0; ks < 4; ++ks) {
            const float* p = WBsrc + (size_t)(it * NM + wave * 16 + l16) * NHID + ks * 32 + l4 * 8;
            float4 u = ldg4(p), v = ldg4(p + 4);
            s16x8 f;
            f[0] = (short)f2bf(u.x); f[1] = (short)f2bf(u.y);
            f[2] = (short)f2bf(u.z); f[3] = (short)f2bf(u.w);
            f[4] = (short)f2bf(v.x); f[5] = (short)f2bf(v.y);
            f[6] = (short)f2bf(v.z); f[7] = (short)f2bf(v.w);
            wB[it][ks] = f;
        }
    float biasA[2] = {BA[wave * 16 + l16], BA[NHID + wave * 16 + l16]};
    float biasB[2] = {BB[wave * 16 + l16], BB[NM + wave * 16 + l16]};

    f32x4 agg[8];
#pragma unroll
    for (int r = 0; r < 8; ++r) agg[r] = (f32x4){0.f, 0.f, 0.f, 0.f};

    const int t0 = chunk * 32;
    const int t1 = (t0 + 32 < NTILE) ? (t0 + 32) : NTILE;

    {
        const int ebase0 = half * EHALF + t0 * TILE_E;
#pragma unroll
        for (int s = 0; s < 2; ++s) {
            const int i = s * 512 + tid;
            const int e = i >> 4, c = i & 15;
            const int cp = c ^ (e & 15);
            gload16(rsg + (size_t)(ebase0 + e) * 128 + cp * 8, (char*)&rs_s[0][0] + i * 16);
        }
    }
    __syncthreads();

    for (int t = t0; t < t1; ++t) {
        const int buf  = (t - t0) & 1;
        const int nbuf = buf ^ 1;
        const int ebase = half * EHALF + t * TILE_E;
        const bool do_next = (t + 1) < t1;

#pragma unroll
        for (int s = 0; s < 2; ++s) {
            const int j = s * 512 + tid;
            const int n = j >> 3, c = j & 7;
            const int cp = c ^ (n & 7);
            gload16(rrT + (size_t)n * NE + ebase + cp * 8, (char*)&rr_s[buf][0] + j * 16);
        }
        if (do_next) {
            const int ebn = ebase + TILE_E;
#pragma unroll
            for (int s = 0; s < 2; ++s) {
                const int i = s * 512 + tid;
                const int e = i >> 4, c = i & 15;
                const int cp = c ^ (e & 15);
                gload16(rsg + (size_t)(ebn + e) * 128 + cp * 8, (char*)&rs_s[nbuf][0] + i * 16);
            }
        }
        if (tid < 128)
            rt_s[buf][tid] = rel_type[((size_t)b * NE + ebase + (tid >> 1)) * NT + (tid & 1)];

#pragma unroll
        for (int et = 0; et < 4; ++et) {
            const int erow = et * 16 + l16;
            s16x8 a0 = *(const s16x8*)swz16c(&rs_s[buf][0], erow, 0 * 64 + l4 * 16);
            s16x8 a1 = *(const s16x8*)swz16c(&rs_s[buf][0], erow, 1 * 64 + l4 * 16);
            s16x8 a2 = *(const s16x8*)swz16c(&rs_s[buf][0], erow, 2 * 64 + l4 * 16);
            s16x8 a3 = *(const s16x8*)swz16c(&rs_s[buf][0], erow, 3 * 64 + l4 * 16);
#pragma unroll
            for (int it = 0; it < 2; ++it) {
                f32x4 c = (f32x4){0.f, 0.f, 0.f, 0.f};
                __builtin_amdgcn_s_setprio(1);
                c = MFMA16(a0, wIW[it][0], c);
                c = MFMA16(a1, wIW[it][1], c);
                c = MFMA16(a2, wIW[it][2], c);
                c = MFMA16(a3, wIW[it][3], c);
                __builtin_amdgcn_s_setprio(0);
#pragma unroll
                for (int r = 0; r < 4; ++r) {
                    const int er = et * 16 + l4 * 4 + r;
                    *(ushort*)swz16(&H_s[buf][it][0], er, (wave * 16 + l16) * 2) =
                        f2bf(fmaxf(c[r] + biasA[it], 0.f));
                }
            }
        }
        __syncthreads();                                   // the ONE barrier

        float macc[4][4];
#pragma unroll
        for (int et = 0; et < 4; ++et)
#pragma unroll
            for (int r = 0; r < 4; ++r) macc[et][r] = 0.f;

#pragma unroll
        for (int et = 0; et < 4; ++et) {
            const int e = et * 16 + l16;
            float2 rtv[4];
#pragma unroll
            for (int r = 0; r < 4; ++r)
                rtv[r] = *(const float2*)&rt_s[buf][(et * 16 + l4 * 4 + r) * 2];
#pragma unroll
            for (int it = 0; it < 2; ++it) {
                f32x4 c = (f32x4){0.f, 0.f, 0.f, 0.f};
                __builtin_amdgcn_s_setprio(1);
#pragma unroll
                for (int ks = 0; ks < 4; ++ks) {
                    s16x8 a = *(const s16x8*)swz16c(&H_s[buf][it][0], e, ks * 64 + l4 * 16);
                    c = MFMA16(a, wB[it][ks], c);
                }
                __builtin_amdgcn_s_setprio(0);
#pragma unroll
                for (int r = 0; r < 4; ++r)
                    macc[et][r] += fmaxf(c[r] + biasB[it], 0.f) * (it ? rtv[r].y : rtv[r].x);
            }
        }

        {
            const int m = wave * 16 + l16;
#pragma unroll
            for (int et = 0; et < 4; ++et) {
                uint2 v;
                v.x = cvtpk(macc[et][0], macc[et][1]);
                v.y = cvtpk(macc[et][2], macc[et][3]);
                *(uint2*)swz8(Mt_s, m, et * 32 + l4 * 8) = v;
            }
            s16x8 bb0 = *(const s16x8*)swz8c(Mt_s, m, 0 * 64 + l4 * 16);
            s16x8 bb1 = *(const s16x8*)swz8c(Mt_s, m, 1 * 64 + l4 * 16);
            __builtin_amdgcn_s_setprio(1);
#pragma unroll
            for (int nt = 0; nt < 8; ++nt) {
                const int n = nt * 16 + l16;
                s16x8 a0 = *(const s16x8*)swz8c(&rr_s[buf][0], n, 0 * 64 + l4 * 16);
                s16x8 a1 = *(const s16x8*)swz8c(&rr_s[buf][0], n, 1 * 64 + l4 * 16);
                agg[nt] = MFMA16(a0, bb0, agg[nt]);
                agg[nt] = MFMA16(a1, bb1, agg[nt]);
            }
            __builtin_amdgcn_s_setprio(0);
        }
    }

    {
        ushort* dst = partial + (size_t)wg * (NN * NM);
        const int m = wave * 16 + l16;
#pragma unroll
        for (int nt = 0; nt < 8; ++nt) {
            uint2 v;
            v.x = cvtpk(agg[nt][0], agg[nt][1]);
            v.y = cvtpk(agg[nt][2], agg[nt][3]);
            *(uint2*)&dst[(size_t)m * NN + nt * 16 + l4 * 4] = v;
        }
    }
}

// ---------------------------------------------------------------------------
// k_out: MFMA node MLP. grid 256 = b*8 + ng (16 n-rows each), block 256.
// xA = sum of 8 bf16 partials; L1 (K=128) -> L2 (K=256) -> L3+residual (f32).
// B-frags read directly from global bf16 weights (L2-resident, shared).
// ---------------------------------------------------------------------------
__global__ __launch_bounds__(256)
void k_out(const ushort* __restrict__ partial,
           const ushort* __restrict__ owbf,
           const float* __restrict__ inputs,
           const float* __restrict__ ob1, const float* __restrict__ ob2,
           const float* __restrict__ ob3,
           float* __restrict__ out)
{
    const int t    = threadIdx.x;
    const int wave = t >> 6;
    const int lane = t & 63;
    const int l16  = lane & 15;
    const int l4   = lane >> 4;
    const int wg   = blockIdx.x;
    const int b    = wg >> 3;
    const int n0   = (wg & 7) * 16;

    __shared__ ushort xA[16 * 128];    // 4 KB  [n][m], 256B rows, swz16
    __shared__ ushort h1A[16 * 256];   // 8 KB  [n][o], 512B rows, swzR
    __shared__ ushort h2A[16 * 256];   // 8 KB

    // reduce 8 bf16 partials -> xA
    for (int u = t; u < 512; u += 256) {
        const int m = u >> 2, g = u & 3;
        float s0 = 0.f, s1 = 0.f, s2 = 0.f, s3 = 0.f;
#pragma unroll
        for (int c = 0; c < 8; ++c) {
            const ushort* p = partial + ((size_t)(b * 8 + c)) * (NN * NM) +
                              (size_t)m * NN + n0 + g * 4;
            s16x4 v = *(const s16x4*)p;
            s0 += bf2f((ushort)v[0]); s1 += bf2f((ushort)v[1]);
            s2 += bf2f((ushort)v[2]); s3 += bf2f((ushort)v[3]);
        }
        *(ushort*)swzR(xA, g * 4 + 0, 256, m * 2) = f2bf(s0);
        *(ushort*)swzR(xA, g * 4 + 1, 256, m * 2) = f2bf(s1);
        *(ushort*)swzR(xA, g * 4 + 2, 256, m * 2) = f2bf(s2);
        *(ushort*)swzR(xA, g * 4 + 3, 256, m * 2) = f2bf(s3);
    }
    __syncthreads();

    // L1: h1 = relu(x @ ow1^T + ob1); wave owns o in [wave*64, wave*64+64)
    {
        s16x8 ka[4];
#pragma unroll
        for (int ks = 0; ks < 4; ++ks)
            ka[ks] = *(const s16x8*)swzRc(xA, l16, 256, ks * 64 + l4 * 16);
#pragma unroll
        for (int ot = 0; ot < 4; ++ot) {
            const int o = wave * 64 + ot * 16 + l16;
            f32x4 c = (f32x4){0.f, 0.f, 0.f, 0.f};
#pragma unroll
            for (int ks = 0; ks < 4; ++ks) {
                s16x8 wb = *(const s16x8*)&owbf[(size_t)o * 128 + ks * 32 + l4 * 8];
                c = MFMA16(ka[ks], wb, c);
            }
            const float bias = ob1[o];
#pragma unroll
            for (int r = 0; r < 4; ++r)
                *(ushort*)swzR(h1A, l4 * 4 + r, 512, o * 2) =
                    f2bf(fmaxf(c[r] + bias, 0.f));
        }
    }
    __syncthreads();

    // L2: h2 = relu(h1 @ ow2^T + ob2), K=256
    {
        s16x8 ka[8];
#pragma unroll
        for (int ks = 0; ks < 8; ++ks)
            ka[ks] = *(const s16x8*)swzRc(h1A, l16, 512, ks * 64 + l4 * 16);
        const ushort* w2b = owbf + 32768;
#pragma unroll
        for (int ot = 0; ot < 4; ++ot) {
            const int o = wave * 64 + ot * 16 + l16;
            f32x4 c = (f32x4){0.f, 0.f, 0.f, 0.f};
#pragma unroll
            for (int ks = 0; ks < 8; ++ks) {
                s16x8 wb = *(const s16x8*)&w2b[(size_t)o * 256 + ks * 32 + l4 * 8];
                c = MFMA16(ka[ks], wb, c);
            }
            const float bias = ob2[o];
#pragma unroll
            for (int r = 0; r < 4; ++r)
                *(ushort*)swzR(h2A, l4 * 4 + r, 512, o * 2) =
                    f2bf(fmaxf(c[r] + bias, 0.f));
        }
    }
    __syncthreads();

    // L3 + residual (f32 epilogue): d = wave*16 + l16
    {
        s16x8 ka[8];
#pragma unroll
        for (int ks = 0; ks < 8; ++ks)
            ka[ks] = *(const s16x8*)swzRc(h2A, l16, 512, ks * 64 + l4 * 16);
        const ushort* w3b = owbf + 98304;
        const int d = wave * 16 + l16;
        f32x4 c = (f32x4){0.f, 0.f, 0.f, 0.f};
#pragma unroll
        for (int ks = 0; ks < 8; ++ks) {
            s16x8 wb = *(const s16x8*)&w3b[(size_t)d * 256 + ks * 32 + l4 * 8];
            c = MFMA16(ka[ks], wb, c);
        }
        const float bias = ob3[d];
#pragma unroll
        for (int r = 0; r < 4; ++r) {
            const int n = n0 + l4 * 4 + r;
            const size_t idx = ((size_t)b * NN + n) * ND + d;
            out[idx] = inputs[idx] + c[r] + bias;
        }
    }
}

extern "C" void kernel_launch(void* const* d_in, const int* in_sizes, int n_in,
                              void* d_out, int out_size, void* d_ws, size_t ws_size,
                              hipStream_t stream)
{
    const float* inputs   = (const float*)d_in[0];
    const float* rel_rec  = (const float*)d_in[1];
    const float* rel_send = (const float*)d_in[2];
    const float* rel_type = (const float*)d_in[3];
    const float* w1  = (const float*)d_in[5];
    const float* b1  = (const float*)d_in[6];
    const float* w2  = (const float*)d_in[7];
    const float* b2  = (const float*)d_in[8];
    const float* w3  = (const float*)d_in[9];
    const float* b3  = (const float*)d_in[10];
    const float* w4  = (const float*)d_in[11];
    const float* b4  = (const float*)d_in[12];
    const float* ow1 = (const float*)d_in[13];
    const float* ob1 = (const float*)d_in[14];
    const float* ow2 = (const float*)d_in[15];
    const float* ob2 = (const float*)d_in[16];
    const float* ow3 = (const float*)d_in[17];
    const float* ob3 = (const float*)d_in[18];

    char* ws = (char*)d_ws;

    k_pre <<<dim3(383), dim3(256), 0, stream>>>(inputs, rel_rec, rel_send,
                                                w1, w3, ow1, ow2, ow3, ws);
    k_edge<<<dim3(256), dim3(512), 0, stream>>>(rel_type,
                                                b1, b2, b3, b4, w2, w4, ws);
    k_out <<<dim3(256), dim3(256), 0, stream>>>((const ushort*)ws,
                                                (const ushort*)(ws + WS_OW),
                                                inputs, ob1, ob2, ob3,
                                                (float*)d_out);
}

// Round 12
// 156.160 us; speedup vs baseline: 1.3523x; 1.2652x over previous
//
#include <hip/hip_runtime.h>
#include <hip/hip_bf16.h>

#define NB 32
#define NN 128
#define NE 16256
#define ND 64
#define NHID 128
#define NM 128
#define NOH 256
#define NT 2
#define EHALF 8128
#define NTILE 127        // 64-edge tiles per half (127*64 == 8128 exactly)
#define TILE_E 64

typedef short s16x8 __attribute__((ext_vector_type(8)));
typedef short s16x4 __attribute__((ext_vector_type(4)));
typedef float f32x4 __attribute__((ext_vector_type(4)));

#define MFMA16(a, b, c) __builtin_amdgcn_mfma_f32_16x16x32_bf16((a), (b), (c), 0, 0, 0)

// ---- ws layout (bytes) ----
// partial: bf16 [256][m=128][n=128]
#define PARTIAL_SZ ((size_t)256 * 128 * 128 * 2)          //  8,388,608
#define WS_RS      (PARTIAL_SZ)                           // ushort[NE][128]
#define RS_SZ      ((size_t)NE * 128 * 2)                 //  4,161,536
#define WS_RRT     (WS_RS + RS_SZ)                        // ushort[128][NE]
#define RRT_SZ     ((size_t)128 * NE * 2)                 //  4,161,536
#define WS_IWA     (WS_RRT + RRT_SZ)                      // ushort[b][half][it][h=128][n=128]
#define IWA_SZ     ((size_t)NB * 2 * 2 * 128 * 128 * 2)   //  8,388,608
#define WS_OW      (WS_IWA + IWA_SZ)                      // frag-ordered bf16 node weights
#define OW_SZ      ((size_t)(32768 + 65536 + 16384) * 2)  //    229,376
// total = 25.3 MB (<= proven 32 MB)

__device__ __forceinline__ ushort f2bf(float x) {
    uint u = __float_as_uint(x);
    return (ushort)((u + 0x7fffu + ((u >> 16) & 1u)) >> 16);
}
__device__ __forceinline__ float bf2f(ushort h) {
    return __uint_as_float(((uint)h) << 16);
}
__device__ __forceinline__ float4 ldg4(const float* p) {
    return *reinterpret_cast<const float4*>(p);
}
// pack 2 f32 -> 2 bf16 in one dword (RNE), single VALU op; low word = first arg
__device__ __forceinline__ uint cvtpk(float lo, float hi) {
    uint r;
    asm("v_cvt_pk_bf16_f32 %0, %1, %2" : "=v"(r) : "v"(lo), "v"(hi));
    return r;
}
// full-granule XOR swizzle for 256B rows: byte ^= (row&15)<<4
__device__ __forceinline__ char* swz16(void* base, int row, int bir) {
    return (char*)base + row * 256 + (bir ^ ((row & 15) << 4));
}
__device__ __forceinline__ const char* swz16c(const void* base, int row, int bir) {
    return (const char*)base + row * 256 + (bir ^ ((row & 15) << 4));
}
// 8-granule XOR swizzle for 128B rows: byte ^= (row&7)<<4
__device__ __forceinline__ char* swz8(void* base, int row, int bir) {
    return (char*)base + row * 128 + (bir ^ ((row & 7) << 4));
}
__device__ __forceinline__ const char* swz8c(const void* base, int row, int bir) {
    return (const char*)base + row * 128 + (bir ^ ((row & 7) << 4));
}
// generic-rowBytes variant (k_out buffers)
__device__ __forceinline__ char* swzR(void* base, int row, int rowBytes, int bir) {
    return (char*)base + row * rowBytes + (bir ^ ((row & 15) << 4));
}
__device__ __forceinline__ const char* swzRc(const void* base, int row, int rowBytes, int bir) {
    return (const char*)base + row * rowBytes + (bir ^ ((row & 15) << 4));
}
// async 16B global->LDS (dest lane-linear; source pre-swizzled per G21)
__device__ __forceinline__ void gload16(const void* g, void* l) {
    __builtin_amdgcn_global_load_lds(
        (const __attribute__((address_space(1))) void*)g,
        (__attribute__((address_space(3))) void*)l, 16, 0, 0);
}

// ---------------------------------------------------------------------------
// k_pre: fused conversions + inpWA precompute + frag-ordered node weights.
// blocks 0..126: rrT transpose+convert; 127..253: rs convert;
// blocks 254..381: inpWA; block 382: ow1/ow2/ow3 -> bf16 fragment order
// ---------------------------------------------------------------------------
__global__ __launch_bounds__(256)
void k_pre(const float* __restrict__ inputs,
           const float* __restrict__ rel_rec, const float* __restrict__ rel_send,
           const float* __restrict__ w1, const float* __restrict__ w3,
           const float* __restrict__ ow1, const float* __restrict__ ow2,
           const float* __restrict__ ow3,
           char* __restrict__ ws)
{
    ushort* rs  = (ushort*)(ws + WS_RS);
    ushort* rrT = (ushort*)(ws + WS_RRT);
    const int t = threadIdx.x;
    const int blk = blockIdx.x;
    __shared__ float lds[128][65];

    if (blk < 127) {                       // rrT: transpose rel_rec -> [n][e] bf16
        const int eb = blk;
        for (int nh = 0; nh < 2; ++nh) {
            __syncthreads();
            for (int i = t; i < 128 * 64; i += 256) {
                int e = i >> 6, n = i & 63;
                lds[e][n] = rel_rec[(size_t)(eb * 128 + e) * 128 + nh * 64 + n];
            }
            __syncthreads();
            for (int i = t; i < 64 * 128; i += 256) {
                int n = i >> 7, e = i & 127;
                rrT[(size_t)(nh * 64 + n) * NE + eb * 128 + e] = f2bf(lds[e][n]);
            }
        }
    } else if (blk < 254) {                // rs: straight convert
        const int eb = blk - 127;
        const float4* src = (const float4*)(rel_send + (size_t)eb * 16384);
        for (int i = t; i < 4096; i += 256) {
            float4 v = src[i];
            ushort4 o;
            o.x = f2bf(v.x); o.y = f2bf(v.y); o.z = f2bf(v.z); o.w = f2bf(v.w);
            *(ushort4*)(rs + (size_t)eb * 16384 + (size_t)i * 4) = o;
        }
    } else if (blk < 382) {                // inpWA precompute (MFMA)
        ushort* iwa = (ushort*)(ws + WS_IWA);
        const int wg = blk - 254;          // 0..127
        const int b = wg >> 2, half = (wg >> 1) & 1, it = wg & 1;
        const float* WA  = (half ? w3 : w1) + (size_t)it * NHID * ND;
        const float* inp = inputs + (size_t)b * NN * ND;
        ushort* dst = iwa + (size_t)wg * NHID * NN;    // [h][n]

        const int lane = t & 63, wave = t >> 6;
        const int l16 = lane & 15, l4 = lane >> 4;

        for (int hh = 0; hh < 2; ++hh) {
            const int ht = wave * 2 + hh;
            s16x8 bf[2];
#pragma unroll
            for (int ks = 0; ks < 2; ++ks) {
                const float* p = WA + (size_t)(ht * 16 + l16) * ND + ks * 32 + l4 * 8;
                float4 u = ldg4(p), v = ldg4(p + 4);
                s16x8 f;
                f[0] = (short)f2bf(u.x); f[1] = (short)f2bf(u.y);
                f[2] = (short)f2bf(u.z); f[3] = (short)f2bf(u.w);
                f[4] = (short)f2bf(v.x); f[5] = (short)f2bf(v.y);
                f[6] = (short)f2bf(v.z); f[7] = (short)f2bf(v.w);
                bf[ks] = f;
            }
            for (int nt = 0; nt < 8; ++nt) {
                s16x8 af[2];
#pragma unroll
                for (int ks = 0; ks < 2; ++ks) {
                    const float* p = inp + (size_t)(nt * 16 + l16) * ND + ks * 32 + l4 * 8;
                    float4 u = ldg4(p), v = ldg4(p + 4);
                    s16x8 f;
                    f[0] = (short)f2bf(u.x); f[1] = (short)f2bf(u.y);
                    f[2] = (short)f2bf(u.z); f[3] = (short)f2bf(u.w);
                    f[4] = (short)f2bf(v.x); f[5] = (short)f2bf(v.y);
                    f[6] = (short)f2bf(v.z); f[7] = (short)f2bf(v.w);
                    af[ks] = f;
                }
                f32x4 c = (f32x4){0.f, 0.f, 0.f, 0.f};
                c = MFMA16(af[0], bf[0], c);
                c = MFMA16(af[1], bf[1], c);
                s16x4 o;
                o[0] = (short)f2bf(c[0]); o[1] = (short)f2bf(c[1]);
                o[2] = (short)f2bf(c[2]); o[3] = (short)f2bf(c[3]);
                *(s16x4*)&dst[(size_t)(ht * 16 + l16) * NN + nt * 16 + l4 * 4] = o;
            }
        }
    } else {                               // node weights -> bf16, FRAG-ORDERED
        ushort* owbf = (ushort*)(ws + WS_OW);
        // elem (i, j): i = (ot*KS + ks)*64 + lane; value = W[o=ot*16+(lane&15)]
        //                                               [k=ks*32+(lane>>4)*8+j]
        for (int i = t; i < 4096; i += 256) {          // ow1: 16 ot x 4 ks, K=128
            const int ln = i & 63, ks = (i >> 6) & 3, ot = i >> 8;
            const float* src = ow1 + (size_t)(ot * 16 + (ln & 15)) * 128 + ks * 32 + (ln >> 4) * 8;
            ushort* d = owbf + (size_t)i * 8;
#pragma unroll
            for (int j = 0; j < 8; ++j) d[j] = f2bf(src[j]);
        }
        for (int i = t; i < 8192; i += 256) {          // ow2: 16 ot x 8 ks, K=256
            const int ln = i & 63, ks = (i >> 6) & 7, ot = i >> 9;
            const float* src = ow2 + (size_t)(ot * 16 + (ln & 15)) * 256 + ks * 32 + (ln >> 4) * 8;
            ushort* d = owbf + 32768 + (size_t)i * 8;
#pragma unroll
            for (int j = 0; j < 8; ++j) d[j] = f2bf(src[j]);
        }
        for (int i = t; i < 2048; i += 256) {          // ow3: 4 dt x 8 ks, K=256
            const int ln = i & 63, ks = (i >> 6) & 7, dt = i >> 9;
            const float* src = ow3 + (size_t)(dt * 16 + (ln & 15)) * 256 + ks * 32 + (ln >> 4) * 8;
            ushort* d = owbf + 98304 + (size_t)i * 8;
#pragma unroll
            for (int j = 0; j < 8; ++j) d[j] = f2bf(src[j]);
        }
    }
}

// ---------------------------------------------------------------------------
// k_edge: ROUND-9 VERBATIM (proven 122 us). grid 256, block 512, 1 block/CU.
// ---------------------------------------------------------------------------
__global__ __launch_bounds__(512, 1)
void k_edge(const float* __restrict__ rel_type,
            const float* __restrict__ b1, const float* __restrict__ b2,
            const float* __restrict__ b3, const float* __restrict__ b4,
            const float* __restrict__ w2, const float* __restrict__ w4,
            char* __restrict__ ws)
{
    const ushort* rsg = (const ushort*)(ws + WS_RS);
    const ushort* rrT = (const ushort*)(ws + WS_RRT);
    const ushort* iwa = (const ushort*)(ws + WS_IWA);
    ushort* partial   = (ushort*)ws;

    const int tid  = threadIdx.x;
    const int wave = tid >> 6;
    const int lane = tid & 63;
    const int l16  = lane & 15;
    const int l4   = lane >> 4;

    const int wg    = blockIdx.x;
    const int b     = wg >> 3;
    const int half  = (wg >> 2) & 1;
    const int chunk = wg & 3;

    const float* BA    = half ? b3 : b1;
    const float* BB    = half ? b4 : b2;
    const float* WBsrc = half ? w4 : w2;

    __shared__ ushort H_s[2][2][64 * 128];  // 64 KB (buf, it), 256B rows
    __shared__ ushort rs_s[2][64 * 128];    // 32 KB, 256B rows
    __shared__ ushort rr_s[2][128 * 64];    // 32 KB, 128B rows
    __shared__ ushort Mt_s[128 * 64];       // 16 KB, 128B rows, wave-private
    __shared__ float  rt_s[2][128];         //  1 KB

    s16x8 wIW[2][4];
    const ushort* iwb = iwa + (size_t)((b * 2 + half) * 2) * NHID * NN;
#pragma unroll
    for (int it = 0; it < 2; ++it)
#pragma unroll
        for (int ks = 0; ks < 4; ++ks)
            wIW[it][ks] = *(const s16x8*)(iwb + (size_t)it * NHID * NN +
                                          (size_t)(wave * 16 + l16) * NN + ks * 32 + l4 * 8);
    s16x8 wB[2][4];
#pragma unroll
    for (int it = 0; it < 2; ++it)
#pragma unroll
        for (int ks = 0; ks < 4; ++ks) {
            const float* p = WBsrc + (size_t)(it * NM + wave * 16 + l16) * NHID + ks * 32 + l4 * 8;
            float4 u = ldg4(p), v = ldg4(p + 4);
            s16x8 f;
            f[0] = (short)f2bf(u.x); f[1] = (short)f2bf(u.y);
            f[2] = (short)f2bf(u.z); f[3] = (short)f2bf(u.w);
            f[4] = (short)f2bf(v.x); f[5] = (short)f2bf(v.y);
            f[6] = (short)f2bf(v.z); f[7] = (short)f2bf(v.w);
            wB[it][ks] = f;
        }
    float biasA[2] = {BA[wave * 16 + l16], BA[NHID + wave * 16 + l16]};
    float biasB[2] = {BB[wave * 16 + l16], BB[NM + wave * 16 + l16]};

    f32x4 agg[8];
#pragma unroll
    for (int r = 0; r < 8; ++r) agg[r] = (f32x4){0.f, 0.f, 0.f, 0.f};

    const int t0 = chunk * 32;
    const int t1 = (t0 + 32 < NTILE) ? (t0 + 32) : NTILE;

    {
        const int ebase0 = half * EHALF + t0 * TILE_E;
#pragma unroll
        for (int s = 0; s < 2; ++s) {
            const int i = s * 512 + tid;
            const int e = i >> 4, c = i & 15;
            const int cp = c ^ (e & 15);
            gload16(rsg + (size_t)(ebase0 + e) * 128 + cp * 8, (char*)&rs_s[0][0] + i * 16);
        }
    }
    __syncthreads();

    for (int t = t0; t < t1; ++t) {
        const int buf  = (t - t0) & 1;
        const int nbuf = buf ^ 1;
        const int ebase = half * EHALF + t * TILE_E;
        const bool do_next = (t + 1) < t1;

#pragma unroll
        for (int s = 0; s < 2; ++s) {
            const int j = s * 512 + tid;
            const int n = j >> 3, c = j & 7;
            const int cp = c ^ (n & 7);
            gload16(rrT + (size_t)n * NE + ebase + cp * 8, (char*)&rr_s[buf][0] + j * 16);
        }
        if (do_next) {
            const int ebn = ebase + TILE_E;
#pragma unroll
            for (int s = 0; s < 2; ++s) {
                const int i = s * 512 + tid;
                const int e = i >> 4, c = i & 15;
                const int cp = c ^ (e & 15);
                gload16(rsg + (size_t)(ebn + e) * 128 + cp * 8, (char*)&rs_s[nbuf][0] + i * 16);
            }
        }
        if (tid < 128)
            rt_s[buf][tid] = rel_type[((size_t)b * NE + ebase + (tid >> 1)) * NT + (tid & 1)];

#pragma unroll
        for (int et = 0; et < 4; ++et) {
            const int erow = et * 16 + l16;
            s16x8 a0 = *(const s16x8*)swz16c(&rs_s[buf][0], erow, 0 * 64 + l4 * 16);
            s16x8 a1 = *(const s16x8*)swz16c(&rs_s[buf][0], erow, 1 * 64 + l4 * 16);
            s16x8 a2 = *(const s16x8*)swz16c(&rs_s[buf][0], erow, 2 * 64 + l4 * 16);
            s16x8 a3 = *(const s16x8*)swz16c(&rs_s[buf][0], erow, 3 * 64 + l4 * 16);
#pragma unroll
            for (int it = 0; it < 2; ++it) {
                f32x4 c = (f32x4){0.f, 0.f, 0.f, 0.f};
                __builtin_amdgcn_s_setprio(1);
                c = MFMA16(a0, wIW[it][0], c);
                c = MFMA16(a1, wIW[it][1], c);
                c = MFMA16(a2, wIW[it][2], c);
                c = MFMA16(a3, wIW[it][3], c);
                __builtin_amdgcn_s_setprio(0);
#pragma unroll
                for (int r = 0; r < 4; ++r) {
                    const int er = et * 16 + l4 * 4 + r;
                    *(ushort*)swz16(&H_s[buf][it][0], er, (wave * 16 + l16) * 2) =
                        f2bf(fmaxf(c[r] + biasA[it], 0.f));
                }
            }
        }
        __syncthreads();                                   // the ONE barrier

        float macc[4][4];
#pragma unroll
        for (int et = 0; et < 4; ++et)
#pragma unroll
            for (int r = 0; r < 4; ++r) macc[et][r] = 0.f;

#pragma unroll
        for (int et = 0; et < 4; ++et) {
            const int e = et * 16 + l16;
            float2 rtv[4];
#pragma unroll
            for (int r = 0; r < 4; ++r)
                rtv[r] = *(const float2*)&rt_s[buf][(et * 16 + l4 * 4 + r) * 2];
#pragma unroll
            for (int it = 0; it < 2; ++it) {
                f32x4 c = (f32x4){0.f, 0.f, 0.f, 0.f};
                __builtin_amdgcn_s_setprio(1);
#pragma unroll
                for (int ks = 0; ks < 4; ++ks) {
                    s16x8 a = *(const s16x8*)swz16c(&H_s[buf][it][0], e, ks * 64 + l4 * 16);
                    c = MFMA16(a, wB[it][ks], c);
                }
                __builtin_amdgcn_s_setprio(0);
#pragma unroll
                for (int r = 0; r < 4; ++r)
                    macc[et][r] += fmaxf(c[r] + biasB[it], 0.f) * (it ? rtv[r].y : rtv[r].x);
            }
        }

        {
            const int m = wave * 16 + l16;
#pragma unroll
            for (int et = 0; et < 4; ++et) {
                uint2 v;
                v.x = cvtpk(macc[et][0], macc[et][1]);
                v.y = cvtpk(macc[et][2], macc[et][3]);
                *(uint2*)swz8(Mt_s, m, et * 32 + l4 * 8) = v;
            }
            s16x8 bb0 = *(const s16x8*)swz8c(Mt_s, m, 0 * 64 + l4 * 16);
            s16x8 bb1 = *(const s16x8*)swz8c(Mt_s, m, 1 * 64 + l4 * 16);
            __builtin_amdgcn_s_setprio(1);
#pragma unroll
            for (int nt = 0; nt < 8; ++nt) {
                const int n = nt * 16 + l16;
                s16x8 a0 = *(const s16x8*)swz8c(&rr_s[buf][0], n, 0 * 64 + l4 * 16);
                s16x8 a1 = *(const s16x8*)swz8c(&rr_s[buf][0], n, 1 * 64 + l4 * 16);
                agg[nt] = MFMA16(a0, bb0, agg[nt]);
                agg[nt] = MFMA16(a1, bb1, agg[nt]);
            }
            __builtin_amdgcn_s_setprio(0);
        }
    }

    {
        ushort* dst = partial + (size_t)wg * (NN * NM);
        const int m = wave * 16 + l16;
#pragma unroll
        for (int nt = 0; nt < 8; ++nt) {
            uint2 v;
            v.x = cvtpk(agg[nt][0], agg[nt][1]);
            v.y = cvtpk(agg[nt][2], agg[nt][3]);
            *(uint2*)&dst[(size_t)m * NN + nt * 16 + l4 * 4] = v;
        }
    }
}

// ---------------------------------------------------------------------------
// k_out: MFMA node MLP, 512 threads (8 waves, 2/SIMD), frag-ordered weights.
// grid 256 = b*8 + ng (16 n-rows). L1/L2: wave owns 2 o-tiles; L3: waves 0-3.
// ---------------------------------------------------------------------------
__global__ __launch_bounds__(512)
void k_out(const ushort* __restrict__ partial,
           const ushort* __restrict__ owbf,
           const float* __restrict__ inputs,
           const float* __restrict__ ob1, const float* __restrict__ ob2,
           const float* __restrict__ ob3,
           float* __restrict__ out)
{
    const int t    = threadIdx.x;
    const int wave = t >> 6;
    const int lane = t & 63;
    const int l16  = lane & 15;
    const int l4   = lane >> 4;
    const int wg   = blockIdx.x;
    const int b    = wg >> 3;
    const int n0   = (wg & 7) * 16;

    __shared__ ushort xA[16 * 128];    // 4 KB  [n][m], 256B rows
    __shared__ ushort h1A[16 * 256];   // 8 KB  [n][o], 512B rows
    __shared__ ushort h2A[16 * 256];   // 8 KB

    // reduce 8 bf16 partials -> xA (512 threads cover all 128m x 4 n-quads)
    {
        const int m = t >> 2, g = t & 3;
        float s0 = 0.f, s1 = 0.f, s2 = 0.f, s3 = 0.f;
#pragma unroll
        for (int c = 0; c < 8; ++c) {
            const ushort* p = partial + ((size_t)(b * 8 + c)) * (NN * NM) +
                              (size_t)m * NN + n0 + g * 4;
            s16x4 v = *(const s16x4*)p;
            s0 += bf2f((ushort)v[0]); s1 += bf2f((ushort)v[1]);
            s2 += bf2f((ushort)v[2]); s3 += bf2f((ushort)v[3]);
        }
        *(ushort*)swzR(xA, g * 4 + 0, 256, m * 2) = f2bf(s0);
        *(ushort*)swzR(xA, g * 4 + 1, 256, m * 2) = f2bf(s1);
        *(ushort*)swzR(xA, g * 4 + 2, 256, m * 2) = f2bf(s2);
        *(ushort*)swzR(xA, g * 4 + 3, 256, m * 2) = f2bf(s3);
    }
    __syncthreads();

    // L1: h1 = relu(x @ ow1^T + ob1); wave owns o-tiles {wave*2, wave*2+1}
    {
        s16x8 ka[4];
#pragma unroll
        for (int ks = 0; ks < 4; ++ks)
            ka[ks] = *(const s16x8*)swzRc(xA, l16, 256, ks * 64 + l4 * 16);
#pragma unroll
        for (int ot = 0; ot < 2; ++ot) {
            const int otg = wave * 2 + ot;
            const int o = otg * 16 + l16;
            f32x4 c = (f32x4){0.f, 0.f, 0.f, 0.f};
#pragma unroll
            for (int ks = 0; ks < 4; ++ks) {
                s16x8 wb = *(const s16x8*)&owbf[((size_t)(otg * 4 + ks) * 64 + lane) * 8];
                c = MFMA16(ka[ks], wb, c);
            }
            const float bias = ob1[o];
#pragma unroll
            for (int r = 0; r < 4; ++r)
                *(ushort*)swzR(h1A, l4 * 4 + r, 512, o * 2) =
                    f2bf(fmaxf(c[r] + bias, 0.f));
        }
    }
    __syncthreads();

    // L2: h2 = relu(h1 @ ow2^T + ob2), K=256
    {
        s16x8 ka[8];
#pragma unroll
        for (int ks = 0; ks < 8; ++ks)
            ka[ks] = *(const s16x8*)swzRc(h1A, l16, 512, ks * 64 + l4 * 16);
        const ushort* w2f = owbf + 32768;
#pragma unroll
        for (int ot = 0; ot < 2; ++ot) {
            const int otg = wave * 2 + ot;
            const int o = otg * 16 + l16;
            f32x4 c = (f32x4){0.f, 0.f, 0.f, 0.f};
#pragma unroll
            for (int ks = 0; ks < 8; ++ks) {
                s16x8 wb = *(const s16x8*)&w2f[((size_t)(otg * 8 + ks) * 64 + lane) * 8];
                c = MFMA16(ka[ks], wb, c);
            }
            const float bias = ob2[o];
#pragma unroll
            for (int r = 0; r < 4; ++r)
                *(ushort*)swzR(h2A, l4 * 4 + r, 512, o * 2) =
                    f2bf(fmaxf(c[r] + bias, 0.f));
        }
    }
    __syncthreads();

    // L3 + residual (f32 epilogue) on waves 0..3: d-tile = wave
    if (wave < 4) {
        s16x8 ka[8];
#pragma unroll
        for (int ks = 0; ks < 8; ++ks)
            ka[ks] = *(const s16x8*)swzRc(h2A, l16, 512, ks * 64 + l4 * 16);
        const ushort* w3f = owbf + 98304;
        const int d = wave * 16 + l16;
        f32x4 c = (f32x4){0.f, 0.f, 0.f, 0.f};
#pragma unroll
        for (int ks = 0; ks < 8; ++ks) {
            s16x8 wb = *(const s16x8*)&w3f[((size_t)(wave * 8 + ks) * 64 + lane) * 8];
            c = MFMA16(ka[ks], wb, c);
        }
        const float bias = ob3[d];
#pragma unroll
        for (int r = 0; r < 4; ++r) {
            const int n = n0 + l4 * 4 + r;
            const size_t idx = ((size_t)b * NN + n) * ND + d;
            out[idx] = inputs[idx] + c[r] + bias;
        }
    }
}

extern "C" void kernel_launch(void* const* d_in, const int* in_sizes, int n_in,
                              void* d_out, int out_size, void* d_ws, size_t ws_size,
                              hipStream_t stream)
{
    const float* inputs   = (const float*)d_in[0];
    const float* rel_rec  = (const float*)d_in[1];
    const float* rel_send = (const float*)d_in[2];
    const float* rel_type = (const float*)d_in[3];
    const float* w1  = (const float*)d_in[5];
    const float* b1  = (const float*)d_in[6];
    const float* w2  = (const float*)d_in[7];
    const float* b2  = (const float*)d_in[8];
    const float* w3  = (const float*)d_in[9];
    const float* b3  = (const float*)d_in[10];
    const float* w4  = (const float*)d_in[11];
    const float* b4  = (const float*)d_in[12];
    const float* ow1 = (const float*)d_in[13];
    const float* ob1 = (const float*)d_in[14];
    const float* ow2 = (const float*)d_in[15];
    const float* ob2 = (const float*)d_in[16];
    const float* ow3 = (const float*)d_in[17];
    const float* ob3 = (const float*)d_in[18];

    char* ws = (char*)d_ws;

    k_pre <<<dim3(383), dim3(256), 0, stream>>>(inputs, rel_rec, rel_send,
                                                w1, w3, ow1, ow2, ow3, ws);
    k_edge<<<dim3(256), dim3(512), 0, stream>>>(rel_type,
                                                b1, b2, b3, b4, w2, w4, ws);
    k_out <<<dim3(256), dim3(512), 0, stream>>>((const ushort*)ws,
                                                (const ushort*)(ws + WS_OW),
                                                inputs, ob1, ob2, ob3,
                                                (float*)d_out);
}